// Round 3
// baseline (698.747 us; speedup 1.0000x reference)
//
#include <hip/hip_runtime.h>
#include <hip/hip_bf16.h>

typedef __bf16 bf16_t;
typedef __bf16 bf16x8 __attribute__((ext_vector_type(8)));
typedef __bf16 bf16x4 __attribute__((ext_vector_type(4)));
typedef float f32x4 __attribute__((ext_vector_type(4)));

#define B_DIM 4
#define NQ 2048
#define NK 2048
#define DMODEL 1024
#define NH 8
#define DHEAD 128

#define AS1 __attribute__((address_space(1)))
#define AS3 __attribute__((address_space(3)))

__device__ __forceinline__ void gl_lds16(const void* g, void* l) {
    __builtin_amdgcn_global_load_lds((const AS1 void*)g, (AS3 void*)l, 16, 0, 0);
}

// ---------------------------------------------------------------------------
// fp32 -> bf16 conversion, 6 pairs selected by blockIdx.y
// ---------------------------------------------------------------------------
struct CvtArgs {
    const float* s[6];
    bf16_t* d[6];
    int n[6];
};

__global__ __launch_bounds__(256) void cvt_k(CvtArgs a) {
    const int p = blockIdx.y;
    const float* s = a.s[p];
    bf16_t* d = a.d[p];
    const int n = a.n[p];
    const int stride = gridDim.x * 256 * 8;
    for (int i = (blockIdx.x * 256 + threadIdx.x) * 8; i < n; i += stride) {
        float4 x0 = *(const float4*)(s + i);
        float4 x1 = *(const float4*)(s + i + 4);
        bf16x8 o = {(bf16_t)x0.x, (bf16_t)x0.y, (bf16_t)x0.z, (bf16_t)x0.w,
                    (bf16_t)x1.x, (bf16_t)x1.y, (bf16_t)x1.z, (bf16_t)x1.w};
        *(bf16x8*)(d + i) = o;
    }
}

// ---------------------------------------------------------------------------
// bf16 GEMM NT with double-buffered global_load_lds prefetch.
// C[M,N] = A[M,K=1024] * B[N,K]^T + bias
// MODE 0: bf16 out; MODE 1: fp32 out = resid + relu(acc+bias); MODE 2: vT scatter
// ---------------------------------------------------------------------------
template <int MODE>
__global__ __launch_bounds__(256) void gemm_bt(
    const bf16_t* __restrict__ A, const bf16_t* __restrict__ Bw,
    const float* __restrict__ bias, const float* resid,
    bf16_t* __restrict__ Cb, float* Cf, int M, int N)
{
    const int K = DMODEL;
    const int tid  = threadIdx.x;
    const int lane = tid & 63;
    const int wv   = tid >> 6;
    const int l16  = lane & 15;
    const int quad = (lane >> 4) & 3;
    const int kc4  = lane >> 4;
    const int wr   = wv >> 1, wc = wv & 1;
    const int rowBase = blockIdx.y * 128;
    const int colBase = blockIdx.x * 128;

    __shared__ bf16_t sA[2][4096];   // 16 KB
    __shared__ bf16_t sB[2][4096];   // 16 KB

    const bf16_t* gA = A + (size_t)(rowBase + wv * 32 + l16) * K + kc4 * 8;
    const bf16_t* gB = Bw + (size_t)(colBase + wv * 32 + l16) * K + kc4 * 8;

    const f32x4 fz = {0.f, 0.f, 0.f, 0.f};
    f32x4 acc[4][4];
#pragma unroll
    for (int i = 0; i < 4; i++)
#pragma unroll
        for (int j = 0; j < 4; j++) acc[i][j] = fz;

    // prologue: stage tile 0 into buf 0
    gl_lds16(gA,                  &sA[0][(wv * 2) * 512]);
    gl_lds16(gA + (size_t)16 * K, &sA[0][(wv * 2 + 1) * 512]);
    gl_lds16(gB,                  &sB[0][(wv * 2) * 512]);
    gl_lds16(gB + (size_t)16 * K, &sB[0][(wv * 2 + 1) * 512]);
    gA += 32; gB += 32;

    const int nIter = K / 32;  // 32
    for (int t = 0; t < nIter; t++) {
        __syncthreads();  // vmcnt(0): tile t landed; all waves done reading buf t-1
        const int cur = t & 1;
        if (t + 1 < nIter) {
            const int nxt = cur ^ 1;
            gl_lds16(gA,                  &sA[nxt][(wv * 2) * 512]);
            gl_lds16(gA + (size_t)16 * K, &sA[nxt][(wv * 2 + 1) * 512]);
            gl_lds16(gB,                  &sB[nxt][(wv * 2) * 512]);
            gl_lds16(gB + (size_t)16 * K, &sB[nxt][(wv * 2 + 1) * 512]);
            gA += 32; gB += 32;
        }

        bf16x8 aF[4], bF[4];
#pragma unroll
        for (int mi = 0; mi < 4; mi++)
            aF[mi] = *(const bf16x8*)(&sA[cur][(wr * 4 + mi) * 512 + (quad * 16 + l16) * 8]);
#pragma unroll
        for (int ni = 0; ni < 4; ni++)
            bF[ni] = *(const bf16x8*)(&sB[cur][(wc * 4 + ni) * 512 + (quad * 16 + l16) * 8]);
#pragma unroll
        for (int mi = 0; mi < 4; mi++)
#pragma unroll
            for (int ni = 0; ni < 4; ni++)
                acc[mi][ni] = __builtin_amdgcn_mfma_f32_16x16x32_bf16(
                    aF[mi], bF[ni], acc[mi][ni], 0, 0, 0);
    }

#pragma unroll
    for (int mi = 0; mi < 4; mi++) {
#pragma unroll
        for (int ni = 0; ni < 4; ni++) {
            int row0 = rowBase + wr * 64 + mi * 16 + quad * 4;
            int col  = colBase + wc * 64 + ni * 16 + l16;
            float bv = bias[col];
            if (MODE == 0) {
#pragma unroll
                for (int r = 0; r < 4; r++)
                    Cb[(size_t)(row0 + r) * N + col] = (bf16_t)(acc[mi][ni][r] + bv);
            } else if (MODE == 1) {
#pragma unroll
                for (int r = 0; r < 4; r++) {
                    float v = acc[mi][ni][r] + bv;
                    v = v > 0.f ? v : 0.f;
                    Cf[(size_t)(row0 + r) * N + col] =
                        resid[(size_t)(row0 + r) * N + col] + v;
                }
            } else {
                int b  = row0 >> 11;
                int n0 = row0 & 2047;
                int hh = col >> 7;
                int dd = col & 127;
                bf16x4 p = {(bf16_t)(acc[mi][ni][0] + bv), (bf16_t)(acc[mi][ni][1] + bv),
                            (bf16_t)(acc[mi][ni][2] + bv), (bf16_t)(acc[mi][ni][3] + bv)};
                *(bf16x4*)(Cb + (size_t)((b * NH + hh) * DHEAD + dd) * NK + n0) = p;
            }
        }
    }
}

// ---------------------------------------------------------------------------
// Flash attention: O = q + softmax(q k^T / sqrt(d)) v
// 256 thr = 4 waves; wave owns 32 q-rows; 128 q-rows/block; 64-key tiles,
// double-buffered K/V prefetch (one barrier per tile).
// LDS: 32K (sK x2) + 32K (sV x2) + 16K (sP, XOR-swizzled) = exactly 80 KB.
// ---------------------------------------------------------------------------
__global__ __launch_bounds__(256) void attn_k(
    const bf16_t* __restrict__ qb, const bf16_t* __restrict__ kb,
    const bf16_t* __restrict__ vT, float* __restrict__ O)
{
    const int tid  = threadIdx.x;
    const int lane = tid & 63;
    const int wv   = tid >> 6;
    const int l16  = lane & 15;
    const int quad = (lane >> 4) & 3;
    const int kc4  = lane >> 4;
    const int qt   = blockIdx.x * 128;
    const int h    = blockIdx.y;
    const int b    = blockIdx.z;
    const int bh   = b * NH + h;

    __shared__ bf16_t sK[2][8192];
    __shared__ bf16_t sV[2][8192];
    __shared__ unsigned sPd[4][1024];  // 32 rows x 32 dwords, XOR-4 swizzle

    const int qrow0 = b * NQ + qt + wv * 32;
    bf16x8 qF[2][4];
#pragma unroll
    for (int rf = 0; rf < 2; rf++)
#pragma unroll
        for (int c = 0; c < 4; c++)
            qF[rf][c] = *(const bf16x8*)(qb + (size_t)(qrow0 + rf * 16 + l16) * DMODEL +
                                         h * DHEAD + c * 32 + quad * 8);

    const f32x4 fz = {0.f, 0.f, 0.f, 0.f};
    f32x4 accO[2][8];
#pragma unroll
    for (int rf = 0; rf < 2; rf++)
#pragma unroll
        for (int d = 0; d < 8; d++) accO[rf][d] = fz;
    float mrow[2][4], lrow[2][4];
#pragma unroll
    for (int rf = 0; rf < 2; rf++)
#pragma unroll
        for (int r = 0; r < 4; r++) { mrow[rf][r] = -3e38f; lrow[rf][r] = 0.f; }
    const float SC2 = 0.08838834764831845f * 1.44269504089f;  // log2(e)/sqrt(128)

    const bf16_t* gK = kb + (size_t)(b * NK + wv * 16 + l16) * DMODEL + h * DHEAD + kc4 * 8;
    const bf16_t* gV = vT + (size_t)(bh * DHEAD + wv * 32 + l16) * NK + kc4 * 8;
    const bool wlane = ((l16 & 1) == 0);

    // prologue: tile 0 into buf 0
#pragma unroll
    for (int s = 0; s < 4; s++)
        gl_lds16(gK + s * 32, &sK[0][(wv * 4 + s) * 512]);
#pragma unroll
    for (int i = 0; i < 2; i++)
#pragma unroll
        for (int kh = 0; kh < 2; kh++)
            gl_lds16(gV + (size_t)i * 16 * NK + kh * 32, &sV[0][((wv * 2 + i) * 2 + kh) * 512]);

    const int nIter = NK / 64;  // 32
    for (int it = 0; it < nIter; it++) {
        __syncthreads();  // tile it landed; all waves done with buf it-1
        const int cur = it & 1;
        if (it + 1 < nIter) {
            const int nxt = cur ^ 1;
            const size_t ko = (size_t)(it + 1) * 64;
#pragma unroll
            for (int s = 0; s < 4; s++)
                gl_lds16(gK + ko * DMODEL + s * 32, &sK[nxt][(wv * 4 + s) * 512]);
#pragma unroll
            for (int i = 0; i < 2; i++)
#pragma unroll
                for (int kh = 0; kh < 2; kh++)
                    gl_lds16(gV + (size_t)i * 16 * NK + ko + kh * 32,
                             &sV[nxt][((wv * 2 + i) * 2 + kh) * 512]);
        }

        // S = q k^T (raw logits)
        f32x4 S[2][4];
#pragma unroll
        for (int rf = 0; rf < 2; rf++)
#pragma unroll
            for (int cb = 0; cb < 4; cb++) S[rf][cb] = fz;
#pragma unroll
        for (int cb = 0; cb < 4; cb++)
#pragma unroll
            for (int c = 0; c < 4; c++) {
                bf16x8 kF = *(const bf16x8*)(&sK[cur][(cb * 4 + c) * 512 + (quad * 16 + l16) * 8]);
                S[0][cb] = __builtin_amdgcn_mfma_f32_16x16x32_bf16(qF[0][c], kF, S[0][cb], 0, 0, 0);
                S[1][cb] = __builtin_amdgcn_mfma_f32_16x16x32_bf16(qF[1][c], kF, S[1][cb], 0, 0, 0);
            }

        // online softmax in exp2 domain
        float alph[2][4];
#pragma unroll
        for (int rf = 0; rf < 2; rf++)
#pragma unroll
            for (int r = 0; r < 4; r++) {
                float mx = fmaxf(fmaxf(S[rf][0][r], S[rf][1][r]),
                                 fmaxf(S[rf][2][r], S[rf][3][r]));
                mx = fmaxf(mx, __shfl_xor(mx, 1));
                mx = fmaxf(mx, __shfl_xor(mx, 2));
                mx = fmaxf(mx, __shfl_xor(mx, 4));
                mx = fmaxf(mx, __shfl_xor(mx, 8));
                float mn = fmaxf(mrow[rf][r], mx);
                float al = exp2f((mrow[rf][r] - mn) * SC2);
                mrow[rf][r] = mn;
                float mc2 = mn * SC2;
                float p0 = exp2f(fmaf(S[rf][0][r], SC2, -mc2));
                float p1 = exp2f(fmaf(S[rf][1][r], SC2, -mc2));
                float p2 = exp2f(fmaf(S[rf][2][r], SC2, -mc2));
                float p3 = exp2f(fmaf(S[rf][3][r], SC2, -mc2));
                S[rf][0][r] = p0; S[rf][1][r] = p1; S[rf][2][r] = p2; S[rf][3][r] = p3;
                lrow[rf][r] = lrow[rf][r] * al + ((p0 + p1) + (p2 + p3));
                alph[rf][r] = al;
            }
#pragma unroll
        for (int rf = 0; rf < 2; rf++)
#pragma unroll
            for (int d = 0; d < 8; d++)
#pragma unroll
                for (int r = 0; r < 4; r++) accO[rf][d][r] *= alph[rf][r];

        // P: C-layout -> packed bf16-pair dwords, XOR-4 swizzled (2-way max = free)
#pragma unroll
        for (int rf = 0; rf < 2; rf++)
#pragma unroll
            for (int cb = 0; cb < 4; cb++)
#pragma unroll
                for (int r = 0; r < 4; r++) {
                    unsigned u = (unsigned)__builtin_bit_cast(unsigned short, (bf16_t)S[rf][cb][r]);
                    unsigned o = __shfl_xor(u, 1);
                    if (wlane) {
                        int row = rf * 16 + quad * 4 + r;
                        int c = cb * 8 + (l16 >> 1);
                        sPd[wv][row * 32 + (c ^ ((row & 7) * 4))] = u | (o << 16);
                    }
                }

        // O += P V
#pragma unroll
        for (int kc = 0; kc < 2; kc++) {
            const int sw = (l16 & 7) * 4;
            bf16x8 pF0 = *(const bf16x8*)(&sPd[wv][l16 * 32 + ((kc * 16 + quad * 4) ^ sw)]);
            bf16x8 pF1 = *(const bf16x8*)(&sPd[wv][(16 + l16) * 32 + ((kc * 16 + quad * 4) ^ sw)]);
#pragma unroll
            for (int db = 0; db < 8; db++) {
                bf16x8 vF = *(const bf16x8*)(&sV[cur][(db * 2 + kc) * 512 + (quad * 16 + l16) * 8]);
                accO[0][db] = __builtin_amdgcn_mfma_f32_16x16x32_bf16(pF0, vF, accO[0][db], 0, 0, 0);
                accO[1][db] = __builtin_amdgcn_mfma_f32_16x16x32_bf16(pF1, vF, accO[1][db], 0, 0, 0);
            }
        }
    }

    // finalize denominators
    float inv[2][4];
#pragma unroll
    for (int rf = 0; rf < 2; rf++)
#pragma unroll
        for (int r = 0; r < 4; r++) {
            float s = lrow[rf][r];
            s += __shfl_xor(s, 1);
            s += __shfl_xor(s, 2);
            s += __shfl_xor(s, 4);
            s += __shfl_xor(s, 8);
            inv[rf][r] = 1.0f / s;
        }

    // O = acc/l + q residual
#pragma unroll
    for (int rf = 0; rf < 2; rf++)
#pragma unroll
        for (int d = 0; d < 8; d++)
#pragma unroll
            for (int r = 0; r < 4; r++) {
                int grow = qrow0 + rf * 16 + quad * 4 + r;
                int gcol = h * DHEAD + d * 16 + l16;
                O[(size_t)grow * DMODEL + gcol] =
                    accO[rf][d][r] * inv[rf][r] + (float)qb[(size_t)grow * DMODEL + gcol];
            }
}

// ---------------------------------------------------------------------------
// LayerNorm over rows of 1024; optional extra bf16 output
// ---------------------------------------------------------------------------
__global__ __launch_bounds__(256) void ln_k(
    const float* __restrict__ X, const float* __restrict__ g,
    const float* __restrict__ bta, float* __restrict__ Yf, bf16_t* Yb)
{
    const int row = blockIdx.x;
    const int t = threadIdx.x;
    float4 x = *(const float4*)(X + (size_t)row * DMODEL + t * 4);
    float s  = x.x + x.y + x.z + x.w;
    float sq = x.x * x.x + x.y * x.y + x.z * x.z + x.w * x.w;
#pragma unroll
    for (int o = 1; o < 64; o <<= 1) {
        s  += __shfl_xor(s, o);
        sq += __shfl_xor(sq, o);
    }
    __shared__ float ls[8];
    int w = t >> 6, ln = t & 63;
    if (ln == 0) { ls[w] = s; ls[4 + w] = sq; }
    __syncthreads();
    s  = ls[0] + ls[1] + ls[2] + ls[3];
    sq = ls[4] + ls[5] + ls[6] + ls[7];
    float mu  = s * (1.f / DMODEL);
    float var = sq * (1.f / DMODEL) - mu * mu;
    float rs  = rsqrtf(var + 1e-5f);
    float4 gv = *(const float4*)(g + t * 4);
    float4 bv = *(const float4*)(bta + t * 4);
    float4 y;
    y.x = (x.x - mu) * rs * gv.x + bv.x;
    y.y = (x.y - mu) * rs * gv.y + bv.y;
    y.z = (x.z - mu) * rs * gv.z + bv.z;
    y.w = (x.w - mu) * rs * gv.w + bv.w;
    *(float4*)(Yf + (size_t)row * DMODEL + t * 4) = y;
    if (Yb) {
        bf16x4 yb = {(bf16_t)y.x, (bf16_t)y.y, (bf16_t)y.z, (bf16_t)y.w};
        *(bf16x4*)(Yb + (size_t)row * DMODEL + t * 4) = yb;
    }
}

// ---------------------------------------------------------------------------
extern "C" void kernel_launch(void* const* d_in, const int* in_sizes, int n_in,
                              void* d_out, int out_size, void* d_ws, size_t ws_size,
                              hipStream_t stream)
{
    const float* Q  = (const float*)d_in[0];
    const float* Kx = (const float*)d_in[1];
    const float* Wq = (const float*)d_in[2];
    const float* bq = (const float*)d_in[3];
    const float* Wk = (const float*)d_in[4];
    const float* bk = (const float*)d_in[5];
    const float* Wv = (const float*)d_in[6];
    const float* bv = (const float*)d_in[7];
    const float* Wo = (const float*)d_in[8];
    const float* bo = (const float*)d_in[9];
    const float* g0 = (const float*)d_in[10];
    const float* b0 = (const float*)d_in[11];
    const float* g1 = (const float*)d_in[12];
    const float* b1 = (const float*)d_in[13];
    float* out = (float*)d_out;

    char* ws = (char*)d_ws;
    bf16_t* Qc  = (bf16_t*)(ws);                  // 16,777,216
    bf16_t* Kc  = (bf16_t*)(ws + 16777216);       // 16,777,216
    bf16_t* Wqc = (bf16_t*)(ws + 33554432);       // 2,097,152
    bf16_t* Wkc = (bf16_t*)(ws + 35651584);
    bf16_t* Wvc = (bf16_t*)(ws + 37748736);
    bf16_t* Woc = (bf16_t*)(ws + 39845888);
    bf16_t* qbb = (bf16_t*)(ws + 41943040);       // 16,777,216
    bf16_t* kbb = (bf16_t*)(ws + 58720256);       // 16,777,216
    bf16_t* vT  = (bf16_t*)(ws + 75497472);       // 16,777,216
    float*  Obuf = (float*)(ws + 92274688);       // 33,554,432
    float*  Lf  = (float*)(ws);                   // alias Qc+Kc (dead after gemm-v)
    bf16_t* Lb  = kbb;                            // alias kb (dead after attn)

    CvtArgs ca;
    ca.s[0] = Q;  ca.d[0] = Qc;  ca.n[0] = B_DIM * NQ * DMODEL;
    ca.s[1] = Kx; ca.d[1] = Kc;  ca.n[1] = B_DIM * NK * DMODEL;
    ca.s[2] = Wq; ca.d[2] = Wqc; ca.n[2] = DMODEL * DMODEL;
    ca.s[3] = Wk; ca.d[3] = Wkc; ca.n[3] = DMODEL * DMODEL;
    ca.s[4] = Wv; ca.d[4] = Wvc; ca.n[4] = DMODEL * DMODEL;
    ca.s[5] = Wo; ca.d[5] = Woc; ca.n[5] = DMODEL * DMODEL;
    cvt_k<<<dim3(512, 6), 256, 0, stream>>>(ca);

    const int M = B_DIM * NQ;  // 8192
    dim3 gg(DMODEL / 128, M / 128);  // (8, 64)

    gemm_bt<0><<<gg, 256, 0, stream>>>(Qc, Wqc, bq, nullptr, qbb, nullptr, M, DMODEL);
    gemm_bt<0><<<gg, 256, 0, stream>>>(Kc, Wkc, bk, nullptr, kbb, nullptr, M, DMODEL);
    gemm_bt<2><<<gg, 256, 0, stream>>>(Kc, Wvc, bv, nullptr, vT, nullptr, M, DMODEL);

    attn_k<<<dim3(NQ / 128, NH, B_DIM), 256, 0, stream>>>(qbb, kbb, vT, Obuf);

    ln_k<<<dim3(M), 256, 0, stream>>>(Obuf, g0, b0, Lf, Lb);

    gemm_bt<1><<<gg, 256, 0, stream>>>(Lb, Woc, bo, Lf, nullptr, Lf, M, DMODEL);

    ln_k<<<dim3(M), 256, 0, stream>>>(Lf, g1, b1, out, nullptr);
}

// Round 4
// 580.291 us; speedup vs baseline: 1.2041x; 1.2041x over previous
//
#include <hip/hip_runtime.h>
#include <hip/hip_bf16.h>

typedef __bf16 bf16_t;
typedef __bf16 bf16x8 __attribute__((ext_vector_type(8)));
typedef __bf16 bf16x4 __attribute__((ext_vector_type(4)));
typedef float f32x4 __attribute__((ext_vector_type(4)));

#define B_DIM 4
#define NQ 2048
#define NK 2048
#define DMODEL 1024
#define NH 8
#define DHEAD 128

#define AS1 __attribute__((address_space(1)))
#define AS3 __attribute__((address_space(3)))

__device__ __forceinline__ void gl_lds16(const void* g, void* l) {
    __builtin_amdgcn_global_load_lds((const AS1 void*)g, (AS3 void*)l, 16, 0, 0);
}

// ---------------------------------------------------------------------------
// fp32 -> bf16 conversion, 6 pairs selected by blockIdx.y
// ---------------------------------------------------------------------------
struct CvtArgs {
    const float* s[6];
    bf16_t* d[6];
    int n[6];
};

__global__ __launch_bounds__(256) void cvt_k(CvtArgs a) {
    const int p = blockIdx.y;
    const float* s = a.s[p];
    bf16_t* d = a.d[p];
    const int n = a.n[p];
    const int stride = gridDim.x * 256 * 8;
    for (int i = (blockIdx.x * 256 + threadIdx.x) * 8; i < n; i += stride) {
        float4 x0 = *(const float4*)(s + i);
        float4 x1 = *(const float4*)(s + i + 4);
        bf16x8 o = {(bf16_t)x0.x, (bf16_t)x0.y, (bf16_t)x0.z, (bf16_t)x0.w,
                    (bf16_t)x1.x, (bf16_t)x1.y, (bf16_t)x1.z, (bf16_t)x1.w};
        *(bf16x8*)(d + i) = o;
    }
}

// ---------------------------------------------------------------------------
// bf16 GEMM NT (round-2 proven): C[M,N] = A[M,K] * B[N,K]^T + bias,
// single-buffered global_load_lds staging.
// MODE 0: bf16 out; MODE 1: fp32 out = resid + relu(acc+bias); MODE 2: vT scatter
// ---------------------------------------------------------------------------
template <int MODE>
__global__ __launch_bounds__(256) void gemm_bt(
    const bf16_t* __restrict__ A, const bf16_t* __restrict__ Bw,
    const float* __restrict__ bias, const float* resid,
    bf16_t* __restrict__ Cb, float* Cf, int M, int N, int K)
{
    const int tid  = threadIdx.x;
    const int lane = tid & 63;
    const int wv   = tid >> 6;
    const int l16  = lane & 15;
    const int quad = (lane >> 4) & 3;
    const int kc4  = lane >> 4;
    const int wr   = wv >> 1, wc = wv & 1;
    const int rowBase = blockIdx.y * 128;
    const int colBase = blockIdx.x * 128;

    __shared__ bf16_t sA[4096];   // 8 KB
    __shared__ bf16_t sB[4096];   // 8 KB

    const bf16_t* gA = A + (size_t)(rowBase + wv * 32 + l16) * K + kc4 * 8;
    const bf16_t* gB = Bw + (size_t)(colBase + wv * 32 + l16) * K + kc4 * 8;
    bf16_t* lA0 = &sA[(wv * 2) * 512];
    bf16_t* lA1 = &sA[(wv * 2 + 1) * 512];
    bf16_t* lB0 = &sB[(wv * 2) * 512];
    bf16_t* lB1 = &sB[(wv * 2 + 1) * 512];

    const f32x4 fz = {0.f, 0.f, 0.f, 0.f};
    f32x4 acc[4][4];
#pragma unroll
    for (int i = 0; i < 4; i++)
#pragma unroll
        for (int j = 0; j < 4; j++) acc[i][j] = fz;

    for (int k0 = 0; k0 < K; k0 += 32) {
        gl_lds16(gA, lA0);
        gl_lds16(gA + (size_t)16 * K, lA1);
        gl_lds16(gB, lB0);
        gl_lds16(gB + (size_t)16 * K, lB1);
        gA += 32; gB += 32;
        __syncthreads();

        bf16x8 aF[4], bF[4];
#pragma unroll
        for (int mi = 0; mi < 4; mi++)
            aF[mi] = *(const bf16x8*)(&sA[(wr * 4 + mi) * 512 + (quad * 16 + l16) * 8]);
#pragma unroll
        for (int ni = 0; ni < 4; ni++)
            bF[ni] = *(const bf16x8*)(&sB[(wc * 4 + ni) * 512 + (quad * 16 + l16) * 8]);
#pragma unroll
        for (int mi = 0; mi < 4; mi++)
#pragma unroll
            for (int ni = 0; ni < 4; ni++)
                acc[mi][ni] = __builtin_amdgcn_mfma_f32_16x16x32_bf16(
                    aF[mi], bF[ni], acc[mi][ni], 0, 0, 0);
        __syncthreads();
    }

#pragma unroll
    for (int mi = 0; mi < 4; mi++) {
#pragma unroll
        for (int ni = 0; ni < 4; ni++) {
            int row0 = rowBase + wr * 64 + mi * 16 + quad * 4;
            int col  = colBase + wc * 64 + ni * 16 + l16;
            float bv = bias[col];
            if (MODE == 0) {
#pragma unroll
                for (int r = 0; r < 4; r++)
                    Cb[(size_t)(row0 + r) * N + col] = (bf16_t)(acc[mi][ni][r] + bv);
            } else if (MODE == 1) {
#pragma unroll
                for (int r = 0; r < 4; r++) {
                    float v = acc[mi][ni][r] + bv;
                    v = v > 0.f ? v : 0.f;
                    Cf[(size_t)(row0 + r) * N + col] =
                        resid[(size_t)(row0 + r) * N + col] + v;
                }
            } else {
                int b  = row0 >> 11;
                int n0 = row0 & 2047;
                int hh = col >> 7;
                int dd = col & 127;
                bf16x4 p = {(bf16_t)(acc[mi][ni][0] + bv), (bf16_t)(acc[mi][ni][1] + bv),
                            (bf16_t)(acc[mi][ni][2] + bv), (bf16_t)(acc[mi][ni][3] + bv)};
                *(bf16x4*)(Cb + (size_t)((b * NH + hh) * DHEAD + dd) * NK + n0) = p;
            }
        }
    }
}

// ---------------------------------------------------------------------------
// Flash attention, barrier-free: 1 wave per block, 32 q-rows per wave.
// K/V fragments loaded DIRECTLY global->VGPR (16B/lane contiguous);
// LDS only for the per-wave P C->A layout round-trip (lgkmcnt-ordered).
// Zero __syncthreads. 2048 one-wave blocks -> 8 independent waves/CU.
// ---------------------------------------------------------------------------
__global__ __launch_bounds__(64, 2) void attn_k(
    const bf16_t* __restrict__ qb, const bf16_t* __restrict__ kb,
    const bf16_t* __restrict__ vT, float* __restrict__ O)
{
    const int lane = threadIdx.x & 63;
    const int l16  = lane & 15;
    const int quad = (lane >> 4) & 3;
    const int h    = blockIdx.y;
    const int b    = blockIdx.z;
    const int bh   = b * NH + h;
    const int qrow0 = b * NQ + blockIdx.x * 32;

    __shared__ unsigned sPd[1024];  // 32 rows x 32 dwords, XOR-4 swizzle, 4 KB

    bf16x8 qF[2][4];
#pragma unroll
    for (int rf = 0; rf < 2; rf++)
#pragma unroll
        for (int c = 0; c < 4; c++)
            qF[rf][c] = *(const bf16x8*)(qb + (size_t)(qrow0 + rf * 16 + l16) * DMODEL +
                                         h * DHEAD + c * 32 + quad * 8);

    const f32x4 fz = {0.f, 0.f, 0.f, 0.f};
    f32x4 accO[2][8];
#pragma unroll
    for (int rf = 0; rf < 2; rf++)
#pragma unroll
        for (int d = 0; d < 8; d++) accO[rf][d] = fz;
    float mrow[2][4], lrow[2][4];
#pragma unroll
    for (int rf = 0; rf < 2; rf++)
#pragma unroll
        for (int r = 0; r < 4; r++) { mrow[rf][r] = -3e38f; lrow[rf][r] = 0.f; }
    const float SC2 = 0.08838834764831845f * 1.44269504089f;  // log2(e)/sqrt(128)

    // per-lane base pointers (16B-aligned contiguous fragment loads)
    const bf16_t* gK = kb + ((size_t)b * NK + l16) * DMODEL + h * DHEAD + quad * 8;
    const bf16_t* gV = vT + ((size_t)bh * DHEAD + l16) * NK + quad * 8;
    const bool wlane = ((l16 & 1) == 0);
    const int sw = (l16 & 7) * 4;

    for (int kt = 0; kt < NK; kt += 64) {
        // ---- S = q k^T : direct-register K fragments ----
        f32x4 S[2][4];
#pragma unroll
        for (int cb = 0; cb < 4; cb++) {
            bf16x8 kF[4];
#pragma unroll
            for (int c = 0; c < 4; c++)
                kF[c] = *(const bf16x8*)(gK + (size_t)(kt + cb * 16) * DMODEL + c * 32);
            S[0][cb] = fz; S[1][cb] = fz;
#pragma unroll
            for (int c = 0; c < 4; c++) {
                S[0][cb] = __builtin_amdgcn_mfma_f32_16x16x32_bf16(qF[0][c], kF[c], S[0][cb], 0, 0, 0);
                S[1][cb] = __builtin_amdgcn_mfma_f32_16x16x32_bf16(qF[1][c], kF[c], S[1][cb], 0, 0, 0);
            }
        }

        // ---- online softmax (exp2 domain) ----
        float alph[2][4];
#pragma unroll
        for (int rf = 0; rf < 2; rf++)
#pragma unroll
            for (int r = 0; r < 4; r++) {
                float mx = fmaxf(fmaxf(S[rf][0][r], S[rf][1][r]),
                                 fmaxf(S[rf][2][r], S[rf][3][r]));
                mx = fmaxf(mx, __shfl_xor(mx, 1));
                mx = fmaxf(mx, __shfl_xor(mx, 2));
                mx = fmaxf(mx, __shfl_xor(mx, 4));
                mx = fmaxf(mx, __shfl_xor(mx, 8));
                float mn = fmaxf(mrow[rf][r], mx);
                float al = exp2f((mrow[rf][r] - mn) * SC2);
                mrow[rf][r] = mn;
                float mc2 = mn * SC2;
                float p0 = exp2f(fmaf(S[rf][0][r], SC2, -mc2));
                float p1 = exp2f(fmaf(S[rf][1][r], SC2, -mc2));
                float p2 = exp2f(fmaf(S[rf][2][r], SC2, -mc2));
                float p3 = exp2f(fmaf(S[rf][3][r], SC2, -mc2));
                S[rf][0][r] = p0; S[rf][1][r] = p1; S[rf][2][r] = p2; S[rf][3][r] = p3;
                lrow[rf][r] = lrow[rf][r] * al + ((p0 + p1) + (p2 + p3));
                alph[rf][r] = al;
            }
#pragma unroll
        for (int rf = 0; rf < 2; rf++)
#pragma unroll
            for (int d = 0; d < 8; d++)
#pragma unroll
                for (int r = 0; r < 4; r++) accO[rf][d][r] *= alph[rf][r];

        // ---- P: C-layout -> packed bf16-pair dwords, XOR-4 swizzle ----
#pragma unroll
        for (int rf = 0; rf < 2; rf++)
#pragma unroll
            for (int cb = 0; cb < 4; cb++)
#pragma unroll
                for (int r = 0; r < 4; r++) {
                    unsigned u = (unsigned)__builtin_bit_cast(unsigned short, (bf16_t)S[rf][cb][r]);
                    unsigned o = __shfl_xor(u, 1);
                    if (wlane) {
                        int row = rf * 16 + quad * 4 + r;
                        int c = cb * 8 + (l16 >> 1);
                        sPd[row * 32 + (c ^ ((row & 7) * 4))] = u | (o << 16);
                    }
                }

        // ---- O += P V : direct-register V fragments ----
#pragma unroll
        for (int kc = 0; kc < 2; kc++) {
            bf16x8 pF0 = *(const bf16x8*)(&sPd[l16 * 32 + ((kc * 16 + quad * 4) ^ sw)]);
            bf16x8 pF1 = *(const bf16x8*)(&sPd[(16 + l16) * 32 + ((kc * 16 + quad * 4) ^ sw)]);
#pragma unroll
            for (int db = 0; db < 8; db++) {
                bf16x8 vF = *(const bf16x8*)(gV + (size_t)(db * 16) * NK + kt + kc * 32);
                accO[0][db] = __builtin_amdgcn_mfma_f32_16x16x32_bf16(pF0, vF, accO[0][db], 0, 0, 0);
                accO[1][db] = __builtin_amdgcn_mfma_f32_16x16x32_bf16(pF1, vF, accO[1][db], 0, 0, 0);
            }
        }
    }

    // finalize denominators
    float inv[2][4];
#pragma unroll
    for (int rf = 0; rf < 2; rf++)
#pragma unroll
        for (int r = 0; r < 4; r++) {
            float s = lrow[rf][r];
            s += __shfl_xor(s, 1);
            s += __shfl_xor(s, 2);
            s += __shfl_xor(s, 4);
            s += __shfl_xor(s, 8);
            inv[rf][r] = 1.0f / s;
        }

    // O = acc/l + q residual
#pragma unroll
    for (int rf = 0; rf < 2; rf++)
#pragma unroll
        for (int d = 0; d < 8; d++)
#pragma unroll
            for (int r = 0; r < 4; r++) {
                int grow = qrow0 + rf * 16 + quad * 4 + r;
                int gcol = h * DHEAD + d * 16 + l16;
                O[(size_t)grow * DMODEL + gcol] =
                    accO[rf][d][r] * inv[rf][r] + (float)qb[(size_t)grow * DMODEL + gcol];
            }
}

// ---------------------------------------------------------------------------
// LayerNorm over rows of 1024; optional extra bf16 output
// ---------------------------------------------------------------------------
__global__ __launch_bounds__(256) void ln_k(
    const float* __restrict__ X, const float* __restrict__ g,
    const float* __restrict__ bta, float* __restrict__ Yf, bf16_t* Yb)
{
    const int row = blockIdx.x;
    const int t = threadIdx.x;
    float4 x = *(const float4*)(X + (size_t)row * DMODEL + t * 4);
    float s  = x.x + x.y + x.z + x.w;
    float sq = x.x * x.x + x.y * x.y + x.z * x.z + x.w * x.w;
#pragma unroll
    for (int o = 1; o < 64; o <<= 1) {
        s  += __shfl_xor(s, o);
        sq += __shfl_xor(sq, o);
    }
    __shared__ float ls[8];
    int w = t >> 6, ln = t & 63;
    if (ln == 0) { ls[w] = s; ls[4 + w] = sq; }
    __syncthreads();
    s  = ls[0] + ls[1] + ls[2] + ls[3];
    sq = ls[4] + ls[5] + ls[6] + ls[7];
    float mu  = s * (1.f / DMODEL);
    float var = sq * (1.f / DMODEL) - mu * mu;
    float rs  = rsqrtf(var + 1e-5f);
    float4 gv = *(const float4*)(g + t * 4);
    float4 bv = *(const float4*)(bta + t * 4);
    float4 y;
    y.x = (x.x - mu) * rs * gv.x + bv.x;
    y.y = (x.y - mu) * rs * gv.y + bv.y;
    y.z = (x.z - mu) * rs * gv.z + bv.z;
    y.w = (x.w - mu) * rs * gv.w + bv.w;
    *(float4*)(Yf + (size_t)row * DMODEL + t * 4) = y;
    if (Yb) {
        bf16x4 yb = {(bf16_t)y.x, (bf16_t)y.y, (bf16_t)y.z, (bf16_t)y.w};
        *(bf16x4*)(Yb + (size_t)row * DMODEL + t * 4) = yb;
    }
}

// ---------------------------------------------------------------------------
extern "C" void kernel_launch(void* const* d_in, const int* in_sizes, int n_in,
                              void* d_out, int out_size, void* d_ws, size_t ws_size,
                              hipStream_t stream)
{
    const float* Q  = (const float*)d_in[0];
    const float* Kx = (const float*)d_in[1];
    const float* Wq = (const float*)d_in[2];
    const float* bq = (const float*)d_in[3];
    const float* Wk = (const float*)d_in[4];
    const float* bk = (const float*)d_in[5];
    const float* Wv = (const float*)d_in[6];
    const float* bv = (const float*)d_in[7];
    const float* Wo = (const float*)d_in[8];
    const float* bo = (const float*)d_in[9];
    const float* g0 = (const float*)d_in[10];
    const float* b0 = (const float*)d_in[11];
    const float* g1 = (const float*)d_in[12];
    const float* b1 = (const float*)d_in[13];
    float* out = (float*)d_out;

    char* ws = (char*)d_ws;
    bf16_t* Qc  = (bf16_t*)(ws);                  // 16,777,216
    bf16_t* Kc  = (bf16_t*)(ws + 16777216);       // 16,777,216
    bf16_t* Wqc = (bf16_t*)(ws + 33554432);       // 2,097,152
    bf16_t* Wkc = (bf16_t*)(ws + 35651584);
    bf16_t* Wvc = (bf16_t*)(ws + 37748736);
    bf16_t* Woc = (bf16_t*)(ws + 39845888);
    bf16_t* qbb = (bf16_t*)(ws + 41943040);       // 16,777,216
    bf16_t* kbb = (bf16_t*)(ws + 58720256);       // 16,777,216
    bf16_t* vT  = (bf16_t*)(ws + 75497472);       // 16,777,216
    float*  Obuf = (float*)(ws + 92274688);       // 33,554,432
    float*  Lf  = (float*)(ws);                   // alias Qc+Kc (dead after gemm-v)
    bf16_t* Lb  = kbb;                            // alias kb (dead after attn)

    CvtArgs ca;
    ca.s[0] = Q;  ca.d[0] = Qc;  ca.n[0] = B_DIM * NQ * DMODEL;
    ca.s[1] = Kx; ca.d[1] = Kc;  ca.n[1] = B_DIM * NK * DMODEL;
    ca.s[2] = Wq; ca.d[2] = Wqc; ca.n[2] = DMODEL * DMODEL;
    ca.s[3] = Wk; ca.d[3] = Wkc; ca.n[3] = DMODEL * DMODEL;
    ca.s[4] = Wv; ca.d[4] = Wvc; ca.n[4] = DMODEL * DMODEL;
    ca.s[5] = Wo; ca.d[5] = Woc; ca.n[5] = DMODEL * DMODEL;
    cvt_k<<<dim3(512, 6), 256, 0, stream>>>(ca);

    const int M = B_DIM * NQ;  // 8192
    dim3 gg(DMODEL / 128, M / 128);  // (8, 64)

    gemm_bt<0><<<gg, 256, 0, stream>>>(Qc, Wqc, bq, nullptr, qbb, nullptr, M, DMODEL, DMODEL);
    gemm_bt<0><<<gg, 256, 0, stream>>>(Kc, Wkc, bk, nullptr, kbb, nullptr, M, DMODEL, DMODEL);
    gemm_bt<2><<<gg, 256, 0, stream>>>(Kc, Wvc, bv, nullptr, vT, nullptr, M, DMODEL, DMODEL);

    attn_k<<<dim3(NQ / 32, NH, B_DIM), 64, 0, stream>>>(qbb, kbb, vT, Obuf);

    ln_k<<<dim3(M), 256, 0, stream>>>(Obuf, g0, b0, Lf, Lb);

    gemm_bt<1><<<gg, 256, 0, stream>>>(Lb, Woc, bo, Lf, nullptr, Lf, M, DMODEL, DMODEL);

    ln_k<<<dim3(M), 256, 0, stream>>>(Lf, g1, b1, out, nullptr);
}

// Round 5
// 460.829 us; speedup vs baseline: 1.5163x; 1.2592x over previous
//
#include <hip/hip_runtime.h>
#include <hip/hip_bf16.h>

typedef __bf16 bf16_t;
typedef __bf16 bf16x8 __attribute__((ext_vector_type(8)));
typedef __bf16 bf16x4 __attribute__((ext_vector_type(4)));
typedef float f32x4 __attribute__((ext_vector_type(4)));

#define B_DIM 4
#define NQ 2048
#define NK 2048
#define DMODEL 1024
#define NH 8
#define DHEAD 128

#define AS1 __attribute__((address_space(1)))
#define AS3 __attribute__((address_space(3)))

__device__ __forceinline__ void gl_lds16(const void* g, void* l) {
    __builtin_amdgcn_global_load_lds((const AS1 void*)g, (AS3 void*)l, 16, 0, 0);
}

// ---------------------------------------------------------------------------
// fp32 -> bf16 conversion, 6 pairs selected by blockIdx.y
// ---------------------------------------------------------------------------
struct CvtArgs {
    const float* s[6];
    bf16_t* d[6];
    int n[6];
};

__global__ __launch_bounds__(256) void cvt_k(CvtArgs a) {
    const int p = blockIdx.y;
    const float* s = a.s[p];
    bf16_t* d = a.d[p];
    const int n = a.n[p];
    const int stride = gridDim.x * 256 * 8;
    for (int i = (blockIdx.x * 256 + threadIdx.x) * 8; i < n; i += stride) {
        float4 x0 = *(const float4*)(s + i);
        float4 x1 = *(const float4*)(s + i + 4);
        bf16x8 o = {(bf16_t)x0.x, (bf16_t)x0.y, (bf16_t)x0.z, (bf16_t)x0.w,
                    (bf16_t)x1.x, (bf16_t)x1.y, (bf16_t)x1.z, (bf16_t)x1.w};
        *(bf16x8*)(d + i) = o;
    }
}

// ---------------------------------------------------------------------------
// Fused Q/K/V projection: z = blockIdx.z selects (A, W, bias, epilogue).
// C[M,N] = A[M,1024] * W[N,1024]^T + bias.  z==2 scatters to vT.
// Inner loop identical to the r2-proven gemm structure.
// ---------------------------------------------------------------------------
__global__ __launch_bounds__(256) void proj_k(
    const bf16_t* Qc, const bf16_t* Kc,
    const bf16_t* Wqc, const bf16_t* Wkc, const bf16_t* Wvc,
    const float* bq, const float* bk, const float* bv,
    bf16_t* qbb, bf16_t* kbb, bf16_t* vT)
{
    const int K = DMODEL, N = DMODEL;
    const int z = blockIdx.z;
    const bf16_t* A  = (z == 0) ? Qc : Kc;
    const bf16_t* Bw = (z == 0) ? Wqc : (z == 1) ? Wkc : Wvc;
    const float* bias = (z == 0) ? bq : (z == 1) ? bk : bv;
    bf16_t* Cb = (z == 0) ? qbb : (z == 1) ? kbb : vT;

    const int tid  = threadIdx.x;
    const int lane = tid & 63;
    const int wv   = tid >> 6;
    const int l16  = lane & 15;
    const int quad = (lane >> 4) & 3;
    const int kc4  = lane >> 4;
    const int wr   = wv >> 1, wc = wv & 1;
    const int rowBase = blockIdx.y * 128;
    const int colBase = blockIdx.x * 128;

    __shared__ bf16_t sA[4096];
    __shared__ bf16_t sB[4096];

    const bf16_t* gA = A + (size_t)(rowBase + wv * 32 + l16) * K + kc4 * 8;
    const bf16_t* gB = Bw + (size_t)(colBase + wv * 32 + l16) * K + kc4 * 8;
    bf16_t* lA0 = &sA[(wv * 2) * 512];
    bf16_t* lA1 = &sA[(wv * 2 + 1) * 512];
    bf16_t* lB0 = &sB[(wv * 2) * 512];
    bf16_t* lB1 = &sB[(wv * 2 + 1) * 512];

    const f32x4 fz = {0.f, 0.f, 0.f, 0.f};
    f32x4 acc[4][4];
#pragma unroll
    for (int i = 0; i < 4; i++)
#pragma unroll
        for (int j = 0; j < 4; j++) acc[i][j] = fz;

    for (int k0 = 0; k0 < K; k0 += 32) {
        gl_lds16(gA, lA0);
        gl_lds16(gA + (size_t)16 * K, lA1);
        gl_lds16(gB, lB0);
        gl_lds16(gB + (size_t)16 * K, lB1);
        gA += 32; gB += 32;
        __syncthreads();

        bf16x8 aF[4], bF[4];
#pragma unroll
        for (int mi = 0; mi < 4; mi++)
            aF[mi] = *(const bf16x8*)(&sA[(wr * 4 + mi) * 512 + (quad * 16 + l16) * 8]);
#pragma unroll
        for (int ni = 0; ni < 4; ni++)
            bF[ni] = *(const bf16x8*)(&sB[(wc * 4 + ni) * 512 + (quad * 16 + l16) * 8]);
#pragma unroll
        for (int mi = 0; mi < 4; mi++)
#pragma unroll
            for (int ni = 0; ni < 4; ni++)
                acc[mi][ni] = __builtin_amdgcn_mfma_f32_16x16x32_bf16(
                    aF[mi], bF[ni], acc[mi][ni], 0, 0, 0);
        __syncthreads();
    }

#pragma unroll
    for (int mi = 0; mi < 4; mi++) {
#pragma unroll
        for (int ni = 0; ni < 4; ni++) {
            int row0 = rowBase + wr * 64 + mi * 16 + quad * 4;
            int col  = colBase + wc * 64 + ni * 16 + l16;
            float bvv = bias[col];
            if (z != 2) {
#pragma unroll
                for (int r = 0; r < 4; r++)
                    Cb[(size_t)(row0 + r) * N + col] = (bf16_t)(acc[mi][ni][r] + bvv);
            } else {
                int b  = row0 >> 11;
                int n0 = row0 & 2047;
                int hh = col >> 7;
                int dd = col & 127;
                bf16x4 p = {(bf16_t)(acc[mi][ni][0] + bvv), (bf16_t)(acc[mi][ni][1] + bvv),
                            (bf16_t)(acc[mi][ni][2] + bvv), (bf16_t)(acc[mi][ni][3] + bvv)};
                *(bf16x4*)(Cb + (size_t)((b * NH + hh) * DHEAD + dd) * NK + n0) = p;
            }
        }
    }
}

// ---------------------------------------------------------------------------
// Wo GEMM (MODE1): Cf = resid + relu(acc + bias)
// ---------------------------------------------------------------------------
__global__ __launch_bounds__(256) void gemm_wo(
    const bf16_t* __restrict__ A, const bf16_t* __restrict__ Bw,
    const float* __restrict__ bias, const float* resid, float* Cf, int M, int N, int K)
{
    const int tid  = threadIdx.x;
    const int lane = tid & 63;
    const int wv   = tid >> 6;
    const int l16  = lane & 15;
    const int quad = (lane >> 4) & 3;
    const int kc4  = lane >> 4;
    const int wr   = wv >> 1, wc = wv & 1;
    const int rowBase = blockIdx.y * 128;
    const int colBase = blockIdx.x * 128;

    __shared__ bf16_t sA[4096];
    __shared__ bf16_t sB[4096];

    const bf16_t* gA = A + (size_t)(rowBase + wv * 32 + l16) * K + kc4 * 8;
    const bf16_t* gB = Bw + (size_t)(colBase + wv * 32 + l16) * K + kc4 * 8;
    bf16_t* lA0 = &sA[(wv * 2) * 512];
    bf16_t* lA1 = &sA[(wv * 2 + 1) * 512];
    bf16_t* lB0 = &sB[(wv * 2) * 512];
    bf16_t* lB1 = &sB[(wv * 2 + 1) * 512];

    const f32x4 fz = {0.f, 0.f, 0.f, 0.f};
    f32x4 acc[4][4];
#pragma unroll
    for (int i = 0; i < 4; i++)
#pragma unroll
        for (int j = 0; j < 4; j++) acc[i][j] = fz;

    for (int k0 = 0; k0 < K; k0 += 32) {
        gl_lds16(gA, lA0);
        gl_lds16(gA + (size_t)16 * K, lA1);
        gl_lds16(gB, lB0);
        gl_lds16(gB + (size_t)16 * K, lB1);
        gA += 32; gB += 32;
        __syncthreads();

        bf16x8 aF[4], bF[4];
#pragma unroll
        for (int mi = 0; mi < 4; mi++)
            aF[mi] = *(const bf16x8*)(&sA[(wr * 4 + mi) * 512 + (quad * 16 + l16) * 8]);
#pragma unroll
        for (int ni = 0; ni < 4; ni++)
            bF[ni] = *(const bf16x8*)(&sB[(wc * 4 + ni) * 512 + (quad * 16 + l16) * 8]);
#pragma unroll
        for (int mi = 0; mi < 4; mi++)
#pragma unroll
            for (int ni = 0; ni < 4; ni++)
                acc[mi][ni] = __builtin_amdgcn_mfma_f32_16x16x32_bf16(
                    aF[mi], bF[ni], acc[mi][ni], 0, 0, 0);
        __syncthreads();
    }

#pragma unroll
    for (int mi = 0; mi < 4; mi++) {
#pragma unroll
        for (int ni = 0; ni < 4; ni++) {
            int row0 = rowBase + wr * 64 + mi * 16 + quad * 4;
            int col  = colBase + wc * 64 + ni * 16 + l16;
            float bvv = bias[col];
#pragma unroll
            for (int r = 0; r < 4; r++) {
                float v = acc[mi][ni][r] + bvv;
                v = v > 0.f ? v : 0.f;
                Cf[(size_t)(row0 + r) * N + col] =
                    resid[(size_t)(row0 + r) * N + col] + v;
            }
        }
    }
}

// ---------------------------------------------------------------------------
// Transposed flash attention: S^T = K Q^T, O^T = V^T P^T.  No P LDS round-trip
// (C->B operand transform via shuffles).  2 waves/block, 64 q-rows/block,
// 64-key tiles.  Grid: x = bh (XCD-locality), y = q-tile.  LDS 32 KB.
// ---------------------------------------------------------------------------
__global__ __launch_bounds__(128, 2) void attn_k(
    const bf16_t* __restrict__ qb, const bf16_t* __restrict__ kb,
    const bf16_t* __restrict__ vT, float* __restrict__ O)
{
    const int tid  = threadIdx.x;
    const int lane = tid & 63;
    const int wv   = tid >> 6;      // 0..1
    const int l16  = lane & 15;
    const int quad = (lane >> 4) & 3;
    const int bh   = blockIdx.x;    // bh-major: same bh -> same XCD
    const int b    = bh >> 3;
    const int h    = bh & 7;
    const int qt   = blockIdx.y * 64;
    const int qrow0 = b * NQ + qt + wv * 32;

    __shared__ bf16_t sK[8192];   // 16 frags (kb0..3 x c0..3) of 1 KB
    __shared__ bf16_t sV[8192];   // 16 frags (db0..7 x kc0..1) of 1 KB

    // Q as B-operand fragments: q = qrow0 + qq*16 + l16, k(d) = c*32 + quad*8
    bf16x8 qF[2][4];
#pragma unroll
    for (int qq = 0; qq < 2; qq++)
#pragma unroll
        for (int c = 0; c < 4; c++)
            qF[qq][c] = *(const bf16x8*)(qb + (size_t)(qrow0 + qq * 16 + l16) * DMODEL +
                                         h * DHEAD + c * 32 + quad * 8);

    const f32x4 fz = {0.f, 0.f, 0.f, 0.f};
    f32x4 accO[8][2];             // O^T frags: [d-block][q-block]
#pragma unroll
    for (int db = 0; db < 8; db++)
#pragma unroll
        for (int qq = 0; qq < 2; qq++) accO[db][qq] = fz;
    float mq[2] = {-3e38f, -3e38f};
    float lq[2] = {0.f, 0.f};
    const float SC2 = 0.08838834764831845f * 1.44269504089f;  // log2(e)/sqrt(128)

    const bf16_t* gKb = kb + ((size_t)b * NK + l16) * DMODEL + h * DHEAD + quad * 8;
    const bf16_t* gVb = vT + ((size_t)bh * DHEAD + l16) * NK + quad * 8;
    const int qa   = (quad & 1) * 2;
    const int srcA = l16 + 16 * qa;
    const int srcB = srcA + 16;
    const bool hi  = (quad >> 1) != 0;

    for (int kt = 0; kt < NK; kt += 64) {
        // ---- stage: wave wv covers kb {2wv,2wv+1} for K, db {4wv..4wv+3} for V
#pragma unroll
        for (int kb2 = 0; kb2 < 2; kb2++) {
            const int kbi = wv * 2 + kb2;
#pragma unroll
            for (int c = 0; c < 4; c++)
                gl_lds16(gKb + (size_t)(kt + kbi * 16) * DMODEL + c * 32,
                         &sK[(kbi * 4 + c) * 512]);
        }
#pragma unroll
        for (int db2 = 0; db2 < 4; db2++) {
            const int dbi = wv * 4 + db2;
#pragma unroll
            for (int kc = 0; kc < 2; kc++)
                gl_lds16(gVb + (size_t)(dbi * 16) * NK + kt + kc * 32,
                         &sV[(dbi * 2 + kc) * 512]);
        }
        __syncthreads();

        // ---- S^T = K Q^T : A = K frags, B = Q frags
        f32x4 S[4][2];
#pragma unroll
        for (int kb4 = 0; kb4 < 4; kb4++) {
            S[kb4][0] = fz; S[kb4][1] = fz;
#pragma unroll
            for (int c = 0; c < 4; c++) {
                bf16x8 kF = *(const bf16x8*)(&sK[(kb4 * 4 + c) * 512 + lane * 8]);
                S[kb4][0] = __builtin_amdgcn_mfma_f32_16x16x32_bf16(kF, qF[0][c], S[kb4][0], 0, 0, 0);
                S[kb4][1] = __builtin_amdgcn_mfma_f32_16x16x32_bf16(kF, qF[1][c], S[kb4][1], 0, 0, 0);
            }
        }

        // ---- online softmax: per lane q = l16 (per qq); keys spread over quads
        float alph[2];
#pragma unroll
        for (int qq = 0; qq < 2; qq++) {
            float mx = fmaxf(fmaxf(fmaxf(S[0][qq][0], S[0][qq][1]), fmaxf(S[0][qq][2], S[0][qq][3])),
                       fmaxf(fmaxf(S[1][qq][0], S[1][qq][1]), fmaxf(S[1][qq][2], S[1][qq][3])));
            mx = fmaxf(mx, fmaxf(fmaxf(fmaxf(S[2][qq][0], S[2][qq][1]), fmaxf(S[2][qq][2], S[2][qq][3])),
                           fmaxf(fmaxf(S[3][qq][0], S[3][qq][1]), fmaxf(S[3][qq][2], S[3][qq][3]))));
            mx = fmaxf(mx, __shfl_xor(mx, 16));
            mx = fmaxf(mx, __shfl_xor(mx, 32));
            float mn = fmaxf(mq[qq], mx);
            float al = exp2f((mq[qq] - mn) * SC2);
            mq[qq] = mn;
            float mc = mn * SC2;
            float sum = 0.f;
#pragma unroll
            for (int kb4 = 0; kb4 < 4; kb4++)
#pragma unroll
                for (int r = 0; r < 4; r++) {
                    float p = exp2f(fmaf(S[kb4][qq][r], SC2, -mc));
                    S[kb4][qq][r] = p;
                    sum += p;
                }
            lq[qq] = lq[qq] * al + sum;   // lane-local partial (this lane's 16 keys)
            alph[qq] = al;
        }
#pragma unroll
        for (int db = 0; db < 8; db++)
#pragma unroll
            for (int qq = 0; qq < 2; qq++)
#pragma unroll
                for (int r = 0; r < 4; r++) accO[db][qq][r] *= alph[qq];

        // ---- P: pack each C-frag into 2 dwords, shuffle into B-operand frags
        uint2 pk[4][2];
#pragma unroll
        for (int kb4 = 0; kb4 < 4; kb4++)
#pragma unroll
            for (int qq = 0; qq < 2; qq++) {
                bf16x4 t = {(bf16_t)S[kb4][qq][0], (bf16_t)S[kb4][qq][1],
                            (bf16_t)S[kb4][qq][2], (bf16_t)S[kb4][qq][3]};
                pk[kb4][qq] = __builtin_bit_cast(uint2, t);
            }
        bf16x8 pF[2][2];
#pragma unroll
        for (int kc = 0; kc < 2; kc++)
#pragma unroll
            for (int qq = 0; qq < 2; qq++) {
                unsigned a0 = (unsigned)__shfl((int)pk[2 * kc][qq].x, srcA);
                unsigned b0 = (unsigned)__shfl((int)pk[2 * kc + 1][qq].x, srcA);
                unsigned a1 = (unsigned)__shfl((int)pk[2 * kc][qq].y, srcA);
                unsigned b1 = (unsigned)__shfl((int)pk[2 * kc + 1][qq].y, srcA);
                unsigned a2 = (unsigned)__shfl((int)pk[2 * kc][qq].x, srcB);
                unsigned b2 = (unsigned)__shfl((int)pk[2 * kc + 1][qq].x, srcB);
                unsigned a3 = (unsigned)__shfl((int)pk[2 * kc][qq].y, srcB);
                unsigned b3 = (unsigned)__shfl((int)pk[2 * kc + 1][qq].y, srcB);
                uint4 w = {hi ? b0 : a0, hi ? b1 : a1, hi ? b2 : a2, hi ? b3 : a3};
                pF[kc][qq] = __builtin_bit_cast(bf16x8, w);
            }

        // ---- O^T += V^T P^T : A = V^T frags, B = P frags
#pragma unroll
        for (int kc = 0; kc < 2; kc++)
#pragma unroll
            for (int db = 0; db < 8; db++) {
                bf16x8 vF = *(const bf16x8*)(&sV[(db * 2 + kc) * 512 + lane * 8]);
                accO[db][0] = __builtin_amdgcn_mfma_f32_16x16x32_bf16(vF, pF[kc][0], accO[db][0], 0, 0, 0);
                accO[db][1] = __builtin_amdgcn_mfma_f32_16x16x32_bf16(vF, pF[kc][1], accO[db][1], 0, 0, 0);
            }
        __syncthreads();
    }

    // finalize denominators (cross-quad partials)
    float inv[2];
#pragma unroll
    for (int qq = 0; qq < 2; qq++) {
        float s = lq[qq];
        s += __shfl_xor(s, 16);
        s += __shfl_xor(s, 32);
        inv[qq] = 1.0f / s;
    }

    // O = acc/l + q residual;  O^T frag: q = l16, d = db*16 + quad*4 + r
#pragma unroll
    for (int qq = 0; qq < 2; qq++) {
        const int grow = qrow0 + qq * 16 + l16;
#pragma unroll
        for (int db = 0; db < 8; db++) {
            const int gcol = h * DHEAD + db * 16 + quad * 4;
            bf16x4 qr = *(const bf16x4*)(qb + (size_t)grow * DMODEL + gcol);
            f32x4 o;
#pragma unroll
            for (int r = 0; r < 4; r++)
                o[r] = accO[db][qq][r] * inv[qq] + (float)qr[r];
            *(f32x4*)(O + (size_t)grow * DMODEL + gcol) = o;
        }
    }
}

// ---------------------------------------------------------------------------
// LayerNorm over rows of 1024; optional extra bf16 output
// ---------------------------------------------------------------------------
__global__ __launch_bounds__(256) void ln_k(
    const float* __restrict__ X, const float* __restrict__ g,
    const float* __restrict__ bta, float* __restrict__ Yf, bf16_t* Yb)
{
    const int row = blockIdx.x;
    const int t = threadIdx.x;
    float4 x = *(const float4*)(X + (size_t)row * DMODEL + t * 4);
    float s  = x.x + x.y + x.z + x.w;
    float sq = x.x * x.x + x.y * x.y + x.z * x.z + x.w * x.w;
#pragma unroll
    for (int o = 1; o < 64; o <<= 1) {
        s  += __shfl_xor(s, o);
        sq += __shfl_xor(sq, o);
    }
    __shared__ float ls[8];
    int w = t >> 6, ln = t & 63;
    if (ln == 0) { ls[w] = s; ls[4 + w] = sq; }
    __syncthreads();
    s  = ls[0] + ls[1] + ls[2] + ls[3];
    sq = ls[4] + ls[5] + ls[6] + ls[7];
    float mu  = s * (1.f / DMODEL);
    float var = sq * (1.f / DMODEL) - mu * mu;
    float rs  = rsqrtf(var + 1e-5f);
    float4 gv = *(const float4*)(g + t * 4);
    float4 bv = *(const float4*)(bta + t * 4);
    float4 y;
    y.x = (x.x - mu) * rs * gv.x + bv.x;
    y.y = (x.y - mu) * rs * gv.y + bv.y;
    y.z = (x.z - mu) * rs * gv.z + bv.z;
    y.w = (x.w - mu) * rs * gv.w + bv.w;
    *(float4*)(Yf + (size_t)row * DMODEL + t * 4) = y;
    if (Yb) {
        bf16x4 yb = {(bf16_t)y.x, (bf16_t)y.y, (bf16_t)y.z, (bf16_t)y.w};
        *(bf16x4*)(Yb + (size_t)row * DMODEL + t * 4) = yb;
    }
}

// ---------------------------------------------------------------------------
extern "C" void kernel_launch(void* const* d_in, const int* in_sizes, int n_in,
                              void* d_out, int out_size, void* d_ws, size_t ws_size,
                              hipStream_t stream)
{
    const float* Q  = (const float*)d_in[0];
    const float* Kx = (const float*)d_in[1];
    const float* Wq = (const float*)d_in[2];
    const float* bq = (const float*)d_in[3];
    const float* Wk = (const float*)d_in[4];
    const float* bk = (const float*)d_in[5];
    const float* Wv = (const float*)d_in[6];
    const float* bv = (const float*)d_in[7];
    const float* Wo = (const float*)d_in[8];
    const float* bo = (const float*)d_in[9];
    const float* g0 = (const float*)d_in[10];
    const float* b0 = (const float*)d_in[11];
    const float* g1 = (const float*)d_in[12];
    const float* b1 = (const float*)d_in[13];
    float* out = (float*)d_out;

    char* ws = (char*)d_ws;
    bf16_t* Qc  = (bf16_t*)(ws);                  // 16,777,216
    bf16_t* Kc  = (bf16_t*)(ws + 16777216);       // 16,777,216
    bf16_t* Wqc = (bf16_t*)(ws + 33554432);       // 2,097,152
    bf16_t* Wkc = (bf16_t*)(ws + 35651584);
    bf16_t* Wvc = (bf16_t*)(ws + 37748736);
    bf16_t* Woc = (bf16_t*)(ws + 39845888);
    bf16_t* qbb = (bf16_t*)(ws + 41943040);       // 16,777,216
    bf16_t* kbb = (bf16_t*)(ws + 58720256);       // 16,777,216
    bf16_t* vT  = (bf16_t*)(ws + 75497472);       // 16,777,216
    float*  Obuf = (float*)(ws + 92274688);       // 33,554,432
    float*  Lf  = (float*)(ws);                   // alias Qc+Kc (dead after proj)
    bf16_t* Lb  = kbb;                            // alias kbb (dead after attn)

    CvtArgs ca;
    ca.s[0] = Q;  ca.d[0] = Qc;  ca.n[0] = B_DIM * NQ * DMODEL;
    ca.s[1] = Kx; ca.d[1] = Kc;  ca.n[1] = B_DIM * NK * DMODEL;
    ca.s[2] = Wq; ca.d[2] = Wqc; ca.n[2] = DMODEL * DMODEL;
    ca.s[3] = Wk; ca.d[3] = Wkc; ca.n[3] = DMODEL * DMODEL;
    ca.s[4] = Wv; ca.d[4] = Wvc; ca.n[4] = DMODEL * DMODEL;
    ca.s[5] = Wo; ca.d[5] = Woc; ca.n[5] = DMODEL * DMODEL;
    cvt_k<<<dim3(512, 6), 256, 0, stream>>>(ca);

    const int M = B_DIM * NQ;  // 8192

    proj_k<<<dim3(DMODEL / 128, M / 128, 3), 256, 0, stream>>>(
        Qc, Kc, Wqc, Wkc, Wvc, bq, bk, bv, qbb, kbb, vT);

    attn_k<<<dim3(B_DIM * NH, NQ / 64), 128, 0, stream>>>(qbb, kbb, vT, Obuf);

    ln_k<<<dim3(M), 256, 0, stream>>>(Obuf, g0, b0, Lf, Lb);

    gemm_wo<<<dim3(DMODEL / 128, M / 128), 256, 0, stream>>>(
        Lb, Woc, bo, Lf, Lf, M, DMODEL, DMODEL);

    ln_k<<<dim3(M), 256, 0, stream>>>(Lf, g1, b1, out, nullptr);
}